// Round 13
// baseline (264.909 us; speedup 1.0000x reference)
//
#include <hip/hip_runtime.h>
#include <hip/hip_bf16.h>

// Problem: CausalSelfAttention  B=2, T=2048, C=1024, H=16, D=64
// Round 13: split-K attention. r12 showed duration = max_serial_tiles x
// ~5.2k cyc (33 tiles=70.6us, 32 tiles=70.3us) -> critical path is the
// longest block's serial k-loop. Fix: (1) qt>=16 blocks split into two
// key-halves -> partial (O bf16, m, l) + merge kernel; max tiles 32->17.
// (2) prefetch issued AFTER barrier B so loads overlap compute instead of
// draining inside the barrier's vmcnt(0). (3) cvt kernels fused into prep.
// ws: Qh 8|Ql 8|Kh 8|Kl 8|xh 8(->Yb)|xl 8(->VT)|[48,56) Op0/Op1|56 ml|
//     WaTh/WaTl live only until qkv (then partials reuse [48,60))|WpT 60-62

#define B_  2
#define T_  2048
#define C_  1024
#define H_  16
#define D_  64
#define M_  (B_ * T_)      // 4096
#define N3_ (3 * C_)       // 3072

typedef __attribute__((ext_vector_type(8))) short s16x8;
typedef __attribute__((ext_vector_type(4))) short s16x4;
typedef __attribute__((ext_vector_type(4))) float f32x4;

typedef const __attribute__((address_space(1))) unsigned int gu32_t;
typedef __attribute__((address_space(3))) unsigned int lu32_t;

__device__ __forceinline__ void gload_lds16(const short* g, short* l) {
    __builtin_amdgcn_global_load_lds((gu32_t*)g, (lu32_t*)l, 16, 0, 0);
}

__device__ __forceinline__ float b2f(unsigned short u) {
    return __uint_as_float(((unsigned)u) << 16);
}
__device__ __forceinline__ unsigned short f2b(float f) {   // RNE bf16 round
    unsigned u = __float_as_uint(f);
    return (unsigned short)((u + 0x7FFFu + ((u >> 16) & 1u)) >> 16);
}
__device__ __forceinline__ float fexp2(float x) {
#if __has_builtin(__builtin_amdgcn_exp2f)
    return __builtin_amdgcn_exp2f(x);
#else
    return exp2f(x);
#endif
}

// ---------------------------------------------------------------------------
// prep: fused input conversions.
//  blocks [0,2048):     x fp32 -> xh/xl bf16 split
//  blocks [2048,2816):  W_attn [1024,3072] -> WaTh/WaTl [3072,1024] T+split
//  blocks [2816,3072):  W_proj [1024,1024] -> WpT [1024,1024] T
// ---------------------------------------------------------------------------
__global__ __launch_bounds__(256) void prep(
    const float* __restrict__ x,  short* __restrict__ xh, short* __restrict__ xl,
    const float* __restrict__ Wa, short* __restrict__ WaTh, short* __restrict__ WaTl,
    const float* __restrict__ Wp, short* __restrict__ WpT)
{
    __shared__ short th[64][80];
    __shared__ short tl[64][80];
    const int tid = threadIdx.x;
    const int bid = blockIdx.x;

    if (bid < 2048) {               // ---- x split ----
        int i = (bid * 256 + tid) * 8;
        float4 a = *(const float4*)&x[i];
        float4 b = *(const float4*)&x[i + 4];
        float v[8] = {a.x, a.y, a.z, a.w, b.x, b.y, b.z, b.w};
        s16x8 h, l;
        #pragma unroll
        for (int j = 0; j < 8; j++) {
            unsigned short hb = f2b(v[j]);
            h[j] = (short)hb;
            l[j] = (short)f2b(v[j] - b2f(hb));
        }
        *(s16x8*)&xh[i] = h;
        *(s16x8*)&xl[i] = l;
        return;
    }

    if (bid < 2816) {               // ---- W_attn transpose+split ----
        int i2 = bid - 2048;        // 0..767 ; grid was (48,16)
        int bx = i2 % 48, by = i2 / 48;
        int k0 = by * 64, n0 = bx * 64;
        {
            int rl = tid >> 4, cl = (tid & 15) * 4;
            #pragma unroll
            for (int i = 0; i < 4; i++) {
                int kr = rl + i * 16;
                float4 v4 = *(const float4*)&Wa[(size_t)(k0 + kr) * N3_ + n0 + cl];
                float v[4] = {v4.x, v4.y, v4.z, v4.w};
                #pragma unroll
                for (int j = 0; j < 4; j++) {
                    unsigned short hb = f2b(v[j]);
                    th[cl + j][kr] = (short)hb;
                    tl[cl + j][kr] = (short)f2b(v[j] - b2f(hb));
                }
            }
        }
        __syncthreads();
        {
            int ro = tid >> 2, co = (tid & 3) * 16;
            *(s16x8*)&WaTh[(size_t)(n0 + ro) * C_ + k0 + co]     = *(s16x8*)&th[ro][co];
            *(s16x8*)&WaTh[(size_t)(n0 + ro) * C_ + k0 + co + 8] = *(s16x8*)&th[ro][co + 8];
            *(s16x8*)&WaTl[(size_t)(n0 + ro) * C_ + k0 + co]     = *(s16x8*)&tl[ro][co];
            *(s16x8*)&WaTl[(size_t)(n0 + ro) * C_ + k0 + co + 8] = *(s16x8*)&tl[ro][co + 8];
        }
        return;
    }

    {                               // ---- W_proj transpose ----
        int i3 = bid - 2816;        // 0..255 ; grid was (16,16)
        int bx = i3 & 15, by = i3 >> 4;
        int k0 = by * 64, n0 = bx * 64;
        {
            int rl = tid >> 4, cl = (tid & 15) * 4;
            #pragma unroll
            for (int i = 0; i < 4; i++) {
                int kr = rl + i * 16;
                float4 v = *(const float4*)&Wp[(size_t)(k0 + kr) * C_ + n0 + cl];
                th[cl + 0][kr] = (short)f2b(v.x);
                th[cl + 1][kr] = (short)f2b(v.y);
                th[cl + 2][kr] = (short)f2b(v.z);
                th[cl + 3][kr] = (short)f2b(v.w);
            }
        }
        __syncthreads();
        {
            int ro = tid >> 2, co = (tid & 3) * 16;
            *(s16x8*)&WpT[(size_t)(n0 + ro) * C_ + k0 + co]     = *(s16x8*)&th[ro][co];
            *(s16x8*)&WpT[(size_t)(n0 + ro) * C_ + k0 + co + 8] = *(s16x8*)&th[ro][co + 8];
        }
    }
}

// ---------------------------------------------------------------------------
// qkv_qk: Q,K columns (N=2048), bf16x3, hi/lo scatter. Q pre-scaled by
// 8*log2(e) (sqrt(D) + exp2-domain fold). (unchanged from r12)
// ---------------------------------------------------------------------------
__global__ __launch_bounds__(256) void qkv_qk(
    const short* __restrict__ Ah, const short* __restrict__ Al,
    const short* __restrict__ BTh, const short* __restrict__ BTl,
    const float* __restrict__ bias,
    short* __restrict__ Qh, short* __restrict__ Ql,
    short* __restrict__ Kh, short* __restrict__ Kl)
{
    __shared__ short Ash[128 * 32], Asl[128 * 32];
    __shared__ short Bsh[128 * 32], Bsl[128 * 32];

    const int tid  = threadIdx.x;
    const int wave = tid >> 6, lane = tid & 63;
    const int wm = wave >> 1, wn = wave & 1;
    const int lm = lane & 15, lq = lane >> 4;
    const int m0 = blockIdx.y * 128, n0 = blockIdx.x * 128;
    const int gr = (lane >> 2);
    const int gc = (lane & 3) * 8;

    f32x4 acc[4][4] = {};

    for (int k0 = 0; k0 < C_; k0 += 32) {
        __syncthreads();
        #pragma unroll
        for (int j = 0; j < 2; j++) {
            int s = wave * 2 + j;
            int row = s * 16 + gr;
            size_t ga = (size_t)(m0 + row) * C_ + k0 + gc;
            size_t gb = (size_t)(n0 + row) * C_ + k0 + gc;
            gload_lds16(&Ah[ga],  &Ash[s * 512]);
            gload_lds16(&Al[ga],  &Asl[s * 512]);
            gload_lds16(&BTh[gb], &Bsh[s * 512]);
            gload_lds16(&BTl[gb], &Bsl[s * 512]);
        }
        __syncthreads();

        s16x8 ah[4], al[4], bh[4], bl[4];
        #pragma unroll
        for (int mi = 0; mi < 4; mi++) {
            int r = wm * 64 + mi * 16 + lm;
            ah[mi] = *(const s16x8*)&Ash[r * 32 + lq * 8];
            al[mi] = *(const s16x8*)&Asl[r * 32 + lq * 8];
        }
        #pragma unroll
        for (int nj = 0; nj < 4; nj++) {
            int r = wn * 64 + nj * 16 + lm;
            bh[nj] = *(const s16x8*)&Bsh[r * 32 + lq * 8];
            bl[nj] = *(const s16x8*)&Bsl[r * 32 + lq * 8];
        }
        #pragma unroll
        for (int mi = 0; mi < 4; mi++)
            #pragma unroll
            for (int nj = 0; nj < 4; nj++) {
                acc[mi][nj] = __builtin_amdgcn_mfma_f32_16x16x32_bf16(
                    ah[mi], bh[nj], acc[mi][nj], 0, 0, 0);
                acc[mi][nj] = __builtin_amdgcn_mfma_f32_16x16x32_bf16(
                    ah[mi], bl[nj], acc[mi][nj], 0, 0, 0);
                acc[mi][nj] = __builtin_amdgcn_mfma_f32_16x16x32_bf16(
                    al[mi], bh[nj], acc[mi][nj], 0, 0, 0);
            }
    }

    #pragma unroll
    for (int nj = 0; nj < 4; nj++) {
        int n = n0 + wn * 64 + nj * 16 + lm;
        float bv = bias[n];
        int isK = n >> 10;
        int c = n & (C_ - 1);
        int h = c >> 6, d = c & (D_ - 1);
        short* dh = isK ? Kh : Qh;
        short* dl = isK ? Kl : Ql;
        float scale = isK ? 1.0f : 11.541560327111708f;   // 8*log2(e)
        #pragma unroll
        for (int mi = 0; mi < 4; mi++) {
            #pragma unroll
            for (int r = 0; r < 4; r++) {
                int m  = m0 + wm * 64 + mi * 16 + lq * 4 + r;
                int bb = m >> 11, t = m & (T_ - 1);
                float v = (acc[mi][nj][r] + bv) * scale;
                size_t idx = (((size_t)bb * H_ + h) * T_ + t) * D_ + d;
                unsigned short hb = f2b(v);
                dh[idx] = (short)hb;
                dl[idx] = (short)f2b(v - b2f(hb));
            }
        }
    }
}

// ---------------------------------------------------------------------------
// qkv_v: V columns (N=1024), single bf16, scatter TRANSPOSED -> VT [B,H,D,T].
// ---------------------------------------------------------------------------
__global__ __launch_bounds__(256) void qkv_v(
    const short* __restrict__ Ah, const short* __restrict__ BTh,
    const float* __restrict__ bias, short* __restrict__ VT)
{
    __shared__ short Ash[128 * 32];
    __shared__ short Bsh[128 * 32];

    const int tid  = threadIdx.x;
    const int wave = tid >> 6, lane = tid & 63;
    const int wm = wave >> 1, wn = wave & 1;
    const int lm = lane & 15, lq = lane >> 4;
    const int m0 = blockIdx.y * 128, n0 = blockIdx.x * 128;
    const int gr = (lane >> 2);
    const int gc = (lane & 3) * 8;

    f32x4 acc[4][4] = {};

    for (int k0 = 0; k0 < C_; k0 += 32) {
        __syncthreads();
        #pragma unroll
        for (int j = 0; j < 2; j++) {
            int s = wave * 2 + j;
            int row = s * 16 + gr;
            gload_lds16(&Ah[(size_t)(m0 + row) * C_ + k0 + gc],  &Ash[s * 512]);
            gload_lds16(&BTh[(size_t)(n0 + row) * C_ + k0 + gc], &Bsh[s * 512]);
        }
        __syncthreads();

        s16x8 af[4], bfr[4];
        #pragma unroll
        for (int mi = 0; mi < 4; mi++)
            af[mi] = *(const s16x8*)&Ash[(wm * 64 + mi * 16 + lm) * 32 + lq * 8];
        #pragma unroll
        for (int nj = 0; nj < 4; nj++)
            bfr[nj] = *(const s16x8*)&Bsh[(wn * 64 + nj * 16 + lm) * 32 + lq * 8];
        #pragma unroll
        for (int mi = 0; mi < 4; mi++)
            #pragma unroll
            for (int nj = 0; nj < 4; nj++)
                acc[mi][nj] = __builtin_amdgcn_mfma_f32_16x16x32_bf16(
                    af[mi], bfr[nj], acc[mi][nj], 0, 0, 0);
    }

    #pragma unroll
    for (int nj = 0; nj < 4; nj++) {
        int n = n0 + wn * 64 + nj * 16 + lm;
        float bv = bias[n];
        int h = n >> 6, d = n & (D_ - 1);
        #pragma unroll
        for (int mi = 0; mi < 4; mi++) {
            #pragma unroll
            for (int r = 0; r < 4; r++) {
                int m  = m0 + wm * 64 + mi * 16 + lq * 4 + r;
                int bb = m >> 11, t = m & (T_ - 1);
                VT[(((size_t)bb * H_ + h) * D_ + d) * T_ + t] =
                    (short)f2b(acc[mi][nj][r] + bv);
            }
        }
    }
}

// ---------------------------------------------------------------------------
// proj: out fp32 [M,C] = Yb(bf16) @ WpT(bf16) + bias.
// ---------------------------------------------------------------------------
__global__ __launch_bounds__(256) void proj_mfma(
    const short* __restrict__ A, const short* __restrict__ BT,
    const float* __restrict__ bias, float* __restrict__ out)
{
    __shared__ short Ash[128 * 32];
    __shared__ short Bsh[128 * 32];

    const int tid  = threadIdx.x;
    const int wave = tid >> 6, lane = tid & 63;
    const int wm = wave >> 1, wn = wave & 1;
    const int lm = lane & 15, lq = lane >> 4;
    const int m0 = blockIdx.y * 128, n0 = blockIdx.x * 128;
    const int gr = (lane >> 2);
    const int gc = (lane & 3) * 8;

    f32x4 acc[4][4] = {};

    for (int k0 = 0; k0 < C_; k0 += 32) {
        __syncthreads();
        #pragma unroll
        for (int j = 0; j < 2; j++) {
            int s = wave * 2 + j;
            int row = s * 16 + gr;
            gload_lds16(&A[(size_t)(m0 + row) * C_ + k0 + gc],  &Ash[s * 512]);
            gload_lds16(&BT[(size_t)(n0 + row) * C_ + k0 + gc], &Bsh[s * 512]);
        }
        __syncthreads();

        s16x8 af[4], bfr[4];
        #pragma unroll
        for (int mi = 0; mi < 4; mi++)
            af[mi] = *(const s16x8*)&Ash[(wm * 64 + mi * 16 + lm) * 32 + lq * 8];
        #pragma unroll
        for (int nj = 0; nj < 4; nj++)
            bfr[nj] = *(const s16x8*)&Bsh[(wn * 64 + nj * 16 + lm) * 32 + lq * 8];
        #pragma unroll
        for (int mi = 0; mi < 4; mi++)
            #pragma unroll
            for (int nj = 0; nj < 4; nj++)
                acc[mi][nj] = __builtin_amdgcn_mfma_f32_16x16x32_bf16(
                    af[mi], bfr[nj], acc[mi][nj], 0, 0, 0);
    }

    #pragma unroll
    for (int nj = 0; nj < 4; nj++) {
        int n = n0 + wn * 64 + nj * 16 + lm;
        float bv = bias[n];
        #pragma unroll
        for (int mi = 0; mi < 4; mi++) {
            #pragma unroll
            for (int r = 0; r < 4; r++) {
                int m = m0 + wm * 64 + mi * 16 + lq * 4 + r;
                out[(size_t)m * C_ + n] = acc[mi][nj][r] + bv;
            }
        }
    }
}

// ---------------------------------------------------------------------------
// MFMA flash attention, S^T layout, split-K for qt>=16.
// grid 1536: xcd=bid&7, r=bid>>3 (0..191); bhl=r&3, u=r>>2 (0..47).
// u<16: unsplit qt=u (<=16 tiles). u>=16: qt=16+((u-16)>>1), part=(u-16)&1;
// part0: kt [0, half), part1: kt [half, qt] (<=17 tiles).
// Prefetch for kt+1 issued AFTER barrier B -> overlaps compute phase.
// Unsplit -> Yb; split -> partial O (bf16, unnormalized) + (m,l) fp32.
// ---------------------------------------------------------------------------
__global__ __launch_bounds__(256) void attn_mfma(
    const short* __restrict__ Qh, const short* __restrict__ Ql,
    const short* __restrict__ Kh, const short* __restrict__ Kl,
    const short* __restrict__ VT, short* __restrict__ Yb,
    short* __restrict__ Op, float2* __restrict__ ml)
{
    __shared__ short Ksh[64][72], Ksl[64][72];   // [key][d]; Q staged here 1st
    __shared__ short Vt [64][72];                // [d][key]
    __shared__ short Ps [4][16][72];             // per-wave P [q][key]

    const int tid  = threadIdx.x;
    const int wave = tid >> 6, lane = tid & 63;
    const int lm   = lane & 15, quad = lane >> 4;

    const int bid = blockIdx.x;
    const int xcd = bid & 7;
    const int r_  = bid >> 3;          // 0..191 per XCD
    const int bhl = r_ & 3;
    const int u   = r_ >> 2;           // 0..47
    int qt, kt0, kt1, part;
    if (u < 16) { qt = u; kt0 = 0; kt1 = qt; part = -1; }
    else {
        int idx = u - 16;              // 0..31
        qt   = 16 + (idx >> 1);
        part = idx & 1;
        int halfk = (qt + 1) >> 1;
        kt0 = part ? halfk : 0;
        kt1 = part ? qt : halfk - 1;
    }
    const int bh  = xcd * 4 + bhl;
    const int b   = bh >> 4, h = bh & (H_ - 1);
    const int q0  = qt * 64;
    const size_t base  = (size_t)bh * T_ * D_;   // Q,K: [b,h,t,d]
    const size_t vbase = (size_t)bh * D_ * T_;   // VT:  [b,h,d,t]

    const int src = tid >> 3;           // staging row 0..31 (+32 for i=1)
    const int sch = (tid & 7) * 8;      // staging col (shorts)

    // ---- stage Q through the K buffers, hoist frags ----
    #pragma unroll
    for (int i = 0; i < 2; i++) {
        int row = i * 32 + src;
        size_t gq = base + (size_t)(q0 + row) * D_ + sch;
        *(s16x8*)&Ksh[row][sch] = *(const s16x8*)&Qh[gq];
        *(s16x8*)&Ksl[row][sch] = *(const s16x8*)&Ql[gq];
    }
    __syncthreads();
    s16x8 bqh[2], bql[2];
    #pragma unroll
    for (int kc = 0; kc < 2; kc++) {
        bqh[kc] = *(const s16x8*)&Ksh[wave * 16 + lm][kc * 32 + quad * 8];
        bql[kc] = *(const s16x8*)&Ksl[wave * 16 + lm][kc * 32 + quad * 8];
    }

    // prefetch k-tile kt0 into registers
    s16x8 pkh[2], pkl[2], pvt[2];
    #pragma unroll
    for (int i = 0; i < 2; i++) {
        int row = i * 32 + src;
        size_t gk = base + (size_t)(kt0 * 64 + row) * D_ + sch;
        pkh[i] = *(const s16x8*)&Kh[gk];
        pkl[i] = *(const s16x8*)&Kl[gk];
        pvt[i] = *(const s16x8*)&VT[vbase + (size_t)row * T_ + kt0 * 64 + sch];
    }

    float mrow = -INFINITY, lrow = 0.f;
    f32x4 O[4] = {};

    for (int kt = kt0; kt <= kt1; kt++) {
        __syncthreads();   // A: prev readers done; prefetch landed (overlapped)
        #pragma unroll
        for (int i = 0; i < 2; i++) {  // VGPR -> LDS
            int row = i * 32 + src;
            *(s16x8*)&Ksh[row][sch] = pkh[i];
            *(s16x8*)&Ksl[row][sch] = pkl[i];
            *(s16x8*)&Vt [row][sch] = pvt[i];
        }
        __syncthreads();   // B: drains lgkm only (no outstanding vmem)
        if (kt < kt1) {    // issue next tile's loads; overlap with compute below
            #pragma unroll
            for (int i = 0; i < 2; i++) {
                int row = i * 32 + src;
                size_t gk = base + (size_t)((kt + 1) * 64 + row) * D_ + sch;
                pkh[i] = *(const s16x8*)&Kh[gk];
                pkl[i] = *(const s16x8*)&Kl[gk];
                pvt[i] = *(const s16x8*)&VT[vbase + (size_t)row * T_ + (kt + 1) * 64 + sch];
            }
        }

        // ---- S^T = K Q^T (bf16x3): A=K (m=key), B=Q (n=q) ----
        f32x4 S[4] = {};
        #pragma unroll
        for (int t = 0; t < 4; t++) {
            #pragma unroll
            for (int kc = 0; kc < 2; kc++) {
                s16x8 kh8 = *(const s16x8*)&Ksh[t * 16 + lm][kc * 32 + quad * 8];
                s16x8 kl8 = *(const s16x8*)&Ksl[t * 16 + lm][kc * 32 + quad * 8];
                S[t] = __builtin_amdgcn_mfma_f32_16x16x32_bf16(kh8, bqh[kc], S[t], 0, 0, 0);
                S[t] = __builtin_amdgcn_mfma_f32_16x16x32_bf16(kl8, bqh[kc], S[t], 0, 0, 0);
                S[t] = __builtin_amdgcn_mfma_f32_16x16x32_bf16(kh8, bql[kc], S[t], 0, 0, 0);
            }
        }

        // causal mask (scale pre-folded into Q)
        const int qg = wave * 16 + lm;
        if (kt == qt) {
            #pragma unroll
            for (int t = 0; t < 4; t++)
                #pragma unroll
                for (int r = 0; r < 4; r++)
                    if ((t * 16 + quad * 4 + r) > qg) S[t][r] = -INFINITY;
        }

        // ---- online softmax in exp2 domain, one q per thread ----
        float rm = -INFINITY;
        #pragma unroll
        for (int t = 0; t < 4; t++)
            #pragma unroll
            for (int r = 0; r < 4; r++) rm = fmaxf(rm, S[t][r]);
        rm = fmaxf(rm, __shfl_xor(rm, 16, 64));
        rm = fmaxf(rm, __shfl_xor(rm, 32, 64));
        float mnew  = fmaxf(mrow, rm);
        float alpha = fexp2(mrow - mnew);
        mrow = mnew;
        float rs = 0.f;
        #pragma unroll
        for (int t = 0; t < 4; t++)
            #pragma unroll
            for (int r = 0; r < 4; r++) {
                S[t][r] = fexp2(S[t][r] - mnew);
                rs += S[t][r];
            }
        rs += __shfl_xor(rs, 16, 64);
        rs += __shfl_xor(rs, 32, 64);
        lrow = lrow * alpha + rs;

        float al[4];
        #pragma unroll
        for (int r = 0; r < 4; r++) al[r] = __shfl(alpha, quad * 4 + r, 64);
        #pragma unroll
        for (int t = 0; t < 4; t++)
            #pragma unroll
            for (int r = 0; r < 4; r++) O[t][r] *= al[r];

        // ---- P^T -> Ps[q][key] (truncating bf16; P in [0,1]) ----
        #pragma unroll
        for (int t = 0; t < 4; t++) {
            s16x4 p;
            #pragma unroll
            for (int r = 0; r < 4; r++)
                p[r] = (short)(__float_as_uint(S[t][r]) >> 16);
            *(s16x4*)&Ps[wave][lm][t * 16 + quad * 4] = p;
        }
        // wave-private slab: no barrier (lgkmcnt ordering within wave)

        // ---- O += P V: A=P (m=q), B=Vt (n=d) ----
        s16x8 ap[2];
        #pragma unroll
        for (int kc = 0; kc < 2; kc++)
            ap[kc] = *(const s16x8*)&Ps[wave][lm][kc * 32 + quad * 8];
        #pragma unroll
        for (int t = 0; t < 4; t++) {
            #pragma unroll
            for (int kc = 0; kc < 2; kc++) {
                s16x8 bv = *(const s16x8*)&Vt[t * 16 + lm][kc * 32 + quad * 8];
                O[t] = __builtin_amdgcn_mfma_f32_16x16x32_bf16(ap[kc], bv, O[t], 0, 0, 0);
            }
        }
    }

    // ---- epilogue ----
    if (part < 0) {
        float li[4];
        #pragma unroll
        for (int r = 0; r < 4; r++)
            li[r] = 1.0f / __shfl(lrow, quad * 4 + r, 64);
        #pragma unroll
        for (int t = 0; t < 4; t++)
            #pragma unroll
            for (int r = 0; r < 4; r++) {
                int q = q0 + wave * 16 + quad * 4 + r;
                int d = t * 16 + lm;
                Yb[((size_t)b * T_ + q) * C_ + h * D_ + d] =
                    (short)f2b(O[t][r] * li[r]);
            }
    } else {
        // partial: Op[part][bh][ql][d] bf16 (unnormalized), ml[part][bh][q]
        size_t obase = ((size_t)part * 32 + bh) * 1024 * 64;
        #pragma unroll
        for (int t = 0; t < 4; t++)
            #pragma unroll
            for (int r = 0; r < 4; r++) {
                int ql = (q0 - 1024) + wave * 16 + quad * 4 + r;
                int d  = t * 16 + lm;
                Op[obase + (size_t)ql * 64 + d] = (short)f2b(O[t][r]);
            }
        if (quad == 0) {
            int ql = (q0 - 1024) + wave * 16 + lm;
            ml[((size_t)part * 32 + bh) * 1024 + ql] = make_float2(mrow, lrow);
        }
    }
}

// ---------------------------------------------------------------------------
// merge: combine the two split-K partials for q in [1024, 2048) of each bh.
// grid 1024 x 256; thread handles 8 d-elements.
// ---------------------------------------------------------------------------
__global__ __launch_bounds__(256) void attn_merge(
    const short* __restrict__ Op, const float2* __restrict__ ml,
    short* __restrict__ Yb)
{
    int eid = blockIdx.x * 256 + threadIdx.x;   // 0 .. 262143
    int dc  = eid & 7;                          // d-chunk
    int ql  = (eid >> 3) & 1023;
    int bh  = eid >> 13;                        // 0..31
    int b   = bh >> 4, h = bh & (H_ - 1);

    float2 m0l = ml[(size_t)bh * 1024 + ql];
    float2 m1l = ml[(size_t)(32 + bh) * 1024 + ql];
    float mm = fmaxf(m0l.x, m1l.x);
    float a0 = fexp2(m0l.x - mm);
    float a1 = fexp2(m1l.x - mm);
    float inv = 1.0f / (m0l.y * a0 + m1l.y * a1);
    a0 *= inv; a1 *= inv;

    size_t ob = ((size_t)bh * 1024 + ql) * 64 + dc * 8;
    s16x8 o0 = *(const s16x8*)&Op[ob];
    s16x8 o1 = *(const s16x8*)&Op[(size_t)32 * 1024 * 64 + ob];
    s16x8 y;
    #pragma unroll
    for (int j = 0; j < 8; j++)
        y[j] = (short)f2b(b2f((unsigned short)o0[j]) * a0 +
                          b2f((unsigned short)o1[j]) * a1);

    int q = 1024 + ql;
    *(s16x8*)&Yb[((size_t)b * T_ + q) * C_ + h * D_ + dc * 8] = y;
}

// ---------------------------------------------------------------------------
extern "C" void kernel_launch(void* const* d_in, const int* in_sizes, int n_in,
                              void* d_out, int out_size, void* d_ws, size_t ws_size,
                              hipStream_t stream)
{
    const float* x      = (const float*)d_in[0];
    const float* W_attn = (const float*)d_in[1];
    const float* b_attn = (const float*)d_in[2];
    const float* W_proj = (const float*)d_in[3];
    const float* b_proj = (const float*)d_in[4];
    float* out = (float*)d_out;

    char* ws = (char*)d_ws;
    const size_t MB = 1024 * 1024;
    short*  Qh   = (short*)(ws);            // 8 MB  [ 0, 8)
    short*  Ql   = (short*)(ws +  8 * MB);  // 8 MB  [ 8,16)
    short*  Kh   = (short*)(ws + 16 * MB);  // 8 MB  [16,24)
    short*  Kl   = (short*)(ws + 24 * MB);  // 8 MB  [24,32)
    short*  xh   = (short*)(ws + 32 * MB);  // 8 MB  [32,40)  dead after qkv_v
    short*  xl   = (short*)(ws + 40 * MB);  // 8 MB  [40,48)  dead after qkv_qk
    short*  WaTh = (short*)(ws + 48 * MB);  // 6 MB  [48,54)  dead after qkv
    short*  WaTl = (short*)(ws + 54 * MB);  // 6 MB  [54,60)  dead after qkv
    short*  WpT  = (short*)(ws + 60 * MB);  // 2 MB  [60,62)
    short*  VT   = (short*)(ws + 40 * MB);  // 8 MB  aliases xl (born at qkv_v)
    short*  Yb   = (short*)(ws + 32 * MB);  // 8 MB  aliases xh (born at attn)
    short*  Op   = (short*)(ws + 48 * MB);  // 8 MB  aliases WaTh+ (born at attn)
    float2* ml   = (float2*)(ws + 56 * MB); // 0.5MB aliases WaTl+ (born at attn)

    prep  <<<dim3(3072), 256, 0, stream>>>(x, xh, xl, W_attn, WaTh, WaTl,
                                           W_proj, WpT);
    qkv_qk<<<dim3(16, 32), 256, 0, stream>>>(xh, xl, WaTh, WaTl, b_attn,
                                             Qh, Ql, Kh, Kl);
    qkv_v <<<dim3(8, 32), 256, 0, stream>>>(xh, WaTh + (size_t)2048 * C_,
                                            b_attn + 2048, VT);
    attn_mfma <<<dim3(1536), 256, 0, stream>>>(Qh, Ql, Kh, Kl, VT, Yb, Op, ml);
    attn_merge<<<dim3(1024), 256, 0, stream>>>(Op, ml, Yb);
    proj_mfma <<<dim3(8, 32), 256, 0, stream>>>(Yb, WpT, b_proj, out);
}